// Round 22
// baseline (375.414 us; speedup 1.0000x reference)
//
#include <hip/hip_runtime.h>
#include <hip/hip_bf16.h>

typedef float  f32x4 __attribute__((ext_vector_type(4)));
typedef short  s16x8 __attribute__((ext_vector_type(8)));

#define NB   1024
#define SEQ  64
#define DIM  512
#define NH   8
#define SCALE 0.044194173824159216f

// per-wave tail-tile slot: XOR swizzle keeps 8-aligned vector reads contiguous
#define TS(r, c) ((r) * 64 + ((c) ^ (((r) & 7) << 3)))

// Compiler memory-ordering fence: forbids reordering LDS reads above other
// lanes' LDS writes (R20 hazard) WITHOUT pinning arithmetic scheduling
// (sched_barrier(0) did, extending live ranges -> R21's 186MB spill).
#define MEM_FENCE() asm volatile("" ::: "memory")

// round-half-up f32->bf16: 2 VALU ops
static __device__ __forceinline__ unsigned short f2bf(float f) {
    unsigned u = __builtin_bit_cast(unsigned, f);
    return (unsigned short)((u + 0x8000u) >> 16);
}

static __device__ __forceinline__ f32x4 mma(s16x8 a, s16x8 b, f32x4 c) {
    return __builtin_amdgcn_mfma_f32_16x16x32_bf16(a, b, c, 0, 0, 0);
}

static __device__ __forceinline__ s16x8 cvt2(float4 a, float4 b) {
    s16x8 x;
    x[0] = (short)f2bf(a.x); x[1] = (short)f2bf(a.y);
    x[2] = (short)f2bf(a.z); x[3] = (short)f2bf(a.w);
    x[4] = (short)f2bf(b.x); x[5] = (short)f2bf(b.y);
    x[6] = (short)f2bf(b.z); x[7] = (short)f2bf(b.w);
    return x;
}

// Pre-kernel: Wq, Wc (f32 [512][512] row-major [k][n]) -> bf16 B-fragment order.
__global__ __launch_bounds__(256) void prep_weights(
    const float* __restrict__ Wq, const float* __restrict__ Wc,
    unsigned short* __restrict__ wf)
{
    int gid  = blockIdx.x * 256 + threadIdx.x;   // 0..65535
    int m    = gid >> 15;
    int tile = (gid >> 10) & 31;
    int ks   = (gid >> 6) & 15;
    int lane = gid & 63;
    const float* W = m ? Wc : Wq;
    int col = tile * 16 + (lane & 15);
    int k0  = ks * 32 + (lane >> 4) * 8;
    unsigned short* dst = wf + (size_t)gid * 8;
#pragma unroll
    for (int j = 0; j < 8; ++j)
        dst[j] = f2bf(W[(size_t)(k0 + j) * DIM + col]);
}

// ====================== Fused kernel: one block = (b, half) ======================
// R22: FOUR-wave blocks so TWO blocks fit the 8-wave register budget.
// R21 proved occupancy is register-limited (192 unified/wave -> 8 waves/CU,
// independent of LDS): a 512-thr block is ONE barrier group; two 256-thr
// blocks are TWO independent groups -> block A's read-stall/store-drain
// overlaps block B's MFMA (2 x 64KB LDS = 128 <= 160 OK).
// Single 64KB region serially reused: stage C (2 x 32-row passes, 16 float4
// live) | GEMM-C | Cp->T (4 x 64x64 XOR tiles = 32KB), cb | stage Q |
// GEMM-Q | Qp->T | in-register tail. Fences = compiler memory clobbers.
// FAILED-mechanism ledger: min-waves clamp (R2/R7), >128-unified multi-block
// (R6/8/9/11/14), reg prefetch across tail (R15/R18), gll across barriers
// (R16), load staggering (R17), unfenced cross-lane reads (R20),
// sched_barrier(0) fences (R21 spill), 512-thr LDS-only shrink (R21 null).
__global__ __launch_bounds__(256) void fused_h(
    const float* __restrict__ query,
    const float* __restrict__ context,
    const float* __restrict__ bq,
    const float* __restrict__ bc,
    const unsigned short* __restrict__ wf,
    float* __restrict__ out)
{
    __shared__ unsigned short S[32768];   // 64 KB: stage buffer == 4 tail tiles + spare

    const int tid  = threadIdx.x;
    const int lane = tid & 63;
    const int wv   = tid >> 6;          // 0..3
    const int l15  = lane & 15;
    const int l4   = lane >> 4;

    // XCD swizzle (grid 2048, %8==0 bijective): the two halves of one b are
    // orig-adjacent -> same XCD -> second act read L2-hot.
    const int i    = blockIdx.x;
    const int orig = (i & 7) * 256 + (i >> 3);
    const int b    = orig >> 1;
    const int half = orig & 1;
    const int h    = half * 4 + wv;     // head this wave owns

    const float* gq = query   + (size_t)b * SEQ * DIM;
    const float* gc = context + (size_t)b * SEQ * DIM;

    const int row0 = tid >> 3;          // 0..31
    const int cw   = tid & 7;

    unsigned short* Tw = S + wv * 4096; // this wave's 64x64 XOR tile
    const f32x4 fz = {0.f, 0.f, 0.f, 0.f};
    f32x4 acc[4][4];

    // stage one 64x512 tile in two 32-row passes (16 float4 live per pass)
#define STAGE(GSRC)                                                            \
    {                                                                          \
        _Pragma("unroll")                                                      \
        for (int pass = 0; pass < 2; ++pass) {                                 \
            const int r_ = row0 + pass * 32;                                   \
            const int wsb_ = (cw >> 2) * 256 + (cw & 3) * 64 + r_;             \
            const float* s_ = (GSRC) + (size_t)r_ * DIM + cw * 8;              \
            float4 ld[16];                                                     \
            _Pragma("unroll")                                                  \
            for (int p = 0; p < 8; ++p) {                                      \
                ld[2 * p]     = *(const float4*)(s_ + p * 64);                 \
                ld[2 * p + 1] = *(const float4*)(s_ + p * 64 + 4);             \
            }                                                                  \
            _Pragma("unroll")                                                  \
            for (int p = 0; p < 8; ++p)                                        \
                *(s16x8*)&S[((p * 512 + wsb_) ^ cw) * 8] =                     \
                    cvt2(ld[2 * p], ld[2 * p + 1]);                            \
        }                                                                      \
    }

#define GEMM16(WFM)                                                            \
    {                                                                          \
        _Pragma("unroll")                                                      \
        for (int ks = 0; ks < 16; ++ks) {                                      \
            const int p_ = ks >> 1, kk_ = ks & 1;                              \
            s16x8 af[4], bf[4];                                                \
            _Pragma("unroll")                                                  \
            for (int mt = 0; mt < 4; ++mt) {                                   \
                const int s_ = p_ * 512 + kk_ * 256 + l4 * 64 + mt * 16 + l15; \
                af[mt] = *(const s16x8*)&S[(s_ ^ (4 * kk_ + l4)) * 8];         \
            }                                                                  \
            _Pragma("unroll")                                                  \
            for (int nt = 0; nt < 4; ++nt)                                     \
                bf[nt] = *(const s16x8*)((WFM) +                               \
                         ((size_t)((h * 4 + nt) * 16 + ks) * 64 + lane) * 8);  \
            _Pragma("unroll")                                                  \
            for (int mt = 0; mt < 4; ++mt)                                     \
                _Pragma("unroll")                                              \
                for (int nt = 0; nt < 4; ++nt)                                 \
                    acc[mt][nt] = mma(af[mt], bf[nt], acc[mt][nt]);            \
        }                                                                      \
    }

    // ---------------- stage C ----------------
    STAGE(gc);
    __syncthreads();

    // ---------------- GEMM-C ----------------
#pragma unroll
    for (int x = 0; x < 4; ++x)
#pragma unroll
        for (int y = 0; y < 4; ++y) acc[x][y] = fz;
    GEMM16(wf + 262144);
    __syncthreads();   // S (C data) dead -> tail tiles may land

    // Cp + bias -> T ; cb frags
#pragma unroll
    for (int nt = 0; nt < 4; ++nt) {
        float bcv = bc[h * 64 + nt * 16 + l15];
#pragma unroll
        for (int mt = 0; mt < 4; ++mt)
#pragma unroll
            for (int r = 0; r < 4; ++r)
                Tw[TS(mt * 16 + l4 * 4 + r, nt * 16 + l15)] = f2bf(acc[mt][nt][r] + bcv);
    }
    MEM_FENCE();   // cross-lane: cb reads other lanes' Cp writes
    s16x8 cb[4][2];
#pragma unroll
    for (int nt = 0; nt < 4; ++nt)
#pragma unroll
        for (int ks = 0; ks < 2; ++ks)
            cb[nt][ks] = *(const s16x8*)&Tw[TS(nt * 16 + l15, ks * 32 + l4 * 8)];
    __syncthreads();   // all waves extracted cb -> region may be overwritten

    // ---------------- stage Q (same buffer; cb in regs) ----------------
    STAGE(gq);
    __syncthreads();

    // ---------------- GEMM-Q ----------------
#pragma unroll
    for (int x = 0; x < 4; ++x)
#pragma unroll
        for (int y = 0; y < 4; ++y) acc[x][y] = fz;
    GEMM16(wf);
    __syncthreads();   // all waves done reading S before T overwrites

    // Qp + bias -> T ; qa/qb frags
#pragma unroll
    for (int nt = 0; nt < 4; ++nt) {
        float bqv = bq[h * 64 + nt * 16 + l15];
#pragma unroll
        for (int mt = 0; mt < 4; ++mt)
#pragma unroll
            for (int r = 0; r < 4; ++r)
                Tw[TS(mt * 16 + l4 * 4 + r, nt * 16 + l15)] = f2bf(acc[mt][nt][r] + bqv);
    }
    MEM_FENCE();   // cross-lane: qa/qb read other lanes' Qp writes
    s16x8 qa[4][2], qb[4][2];
#pragma unroll
    for (int mt = 0; mt < 4; ++mt)
#pragma unroll
        for (int ks = 0; ks < 2; ++ks)
            qa[mt][ks] = *(const s16x8*)&Tw[TS(mt * 16 + l15, ks * 32 + l4 * 8)];
#pragma unroll
    for (int nt = 0; nt < 4; ++nt)
#pragma unroll
        for (int ks = 0; ks < 2; ++ks) {
            s16x8 v;
#pragma unroll
            for (int j = 0; j < 8; ++j)
                v[j] = (short)Tw[TS(ks * 32 + l4 * 8 + j, nt * 16 + l15)];
            qb[nt][ks] = v;
        }

    // ---------------- attention tail ----------------
    f32x4 Sc[4][4];
#pragma unroll
    for (int x = 0; x < 4; ++x)
#pragma unroll
        for (int y = 0; y < 4; ++y) Sc[x][y] = fz;
#pragma unroll
    for (int ks = 0; ks < 2; ++ks)
#pragma unroll
        for (int mt = 0; mt < 4; ++mt)
#pragma unroll
            for (int nt = 0; nt < 4; ++nt)
                Sc[mt][nt] = mma(qa[mt][ks], cb[nt][ks], Sc[mt][nt]);

    // softmax over keys (rows): P1 -> T
#pragma unroll
    for (int mt = 0; mt < 4; ++mt)
#pragma unroll
        for (int r = 0; r < 4; ++r) {
            float m = fmaxf(fmaxf(Sc[mt][0][r], Sc[mt][1][r]),
                            fmaxf(Sc[mt][2][r], Sc[mt][3][r]));
            m = fmaxf(m, __shfl_xor(m, 1));
            m = fmaxf(m, __shfl_xor(m, 2));
            m = fmaxf(m, __shfl_xor(m, 4));
            m = fmaxf(m, __shfl_xor(m, 8));
            float e[4], s = 0.f;
#pragma unroll
            for (int nt = 0; nt < 4; ++nt) { e[nt] = __expf(SCALE * (Sc[mt][nt][r] - m)); s += e[nt]; }
            s += __shfl_xor(s, 1);
            s += __shfl_xor(s, 2);
            s += __shfl_xor(s, 4);
            s += __shfl_xor(s, 8);
            float inv = 1.f / s;
            int r3 = mt * 16 + l4 * 4 + r;
#pragma unroll
            for (int nt = 0; nt < 4; ++nt)
                Tw[TS(r3, nt * 16 + l15)] = f2bf(e[nt] * inv);
        }
    MEM_FENCE();   // cross-lane: pa reads other lanes' P1 writes

    s16x8 pa[4][2];
#pragma unroll
    for (int mt = 0; mt < 4; ++mt)
#pragma unroll
        for (int ks = 0; ks < 2; ++ks)
            pa[mt][ks] = *(const s16x8*)&Tw[TS(mt * 16 + l15, ks * 32 + l4 * 8)];

    // softmax over queries (cols): P2^T -> T
#pragma unroll
    for (int nt = 0; nt < 4; ++nt) {
        float m = -1e30f;
#pragma unroll
        for (int mt = 0; mt < 4; ++mt)
#pragma unroll
            for (int r = 0; r < 4; ++r) m = fmaxf(m, Sc[mt][nt][r]);
        m = fmaxf(m, __shfl_xor(m, 16));
        m = fmaxf(m, __shfl_xor(m, 32));
        float ee[4][4], s = 0.f;
#pragma unroll
        for (int mt = 0; mt < 4; ++mt)
#pragma unroll
            for (int r = 0; r < 4; ++r) { ee[mt][r] = __expf(SCALE * (Sc[mt][nt][r] - m)); s += ee[mt][r]; }
        s += __shfl_xor(s, 16);
        s += __shfl_xor(s, 32);
        float inv = 1.f / s;
        int krow = nt * 16 + l15;
#pragma unroll
        for (int mt = 0; mt < 4; ++mt)
#pragma unroll
            for (int r = 0; r < 4; ++r)
                Tw[TS(krow, mt * 16 + l4 * 4 + r)] = f2bf(ee[mt][r] * inv);
    }
    MEM_FENCE();   // cross-lane: p2a reads other lanes' P2^T writes

    // c_coattn = P1 @ Cp^T ; store
    f32x4 O[4][4];
#pragma unroll
    for (int x = 0; x < 4; ++x)
#pragma unroll
        for (int y = 0; y < 4; ++y) O[x][y] = fz;
#pragma unroll
    for (int ks = 0; ks < 2; ++ks)
#pragma unroll
        for (int mt = 0; mt < 4; ++mt)
#pragma unroll
            for (int nt = 0; nt < 4; ++nt)
                O[mt][nt] = mma(pa[mt][ks], cb[nt][ks], O[mt][nt]);

    float* cO = out;
#pragma unroll
    for (int mt = 0; mt < 4; ++mt)
#pragma unroll
        for (int nt = 0; nt < 4; ++nt)
#pragma unroll
            for (int r = 0; r < 4; ++r) {
                int qrow = mt * 16 + l4 * 4 + r;
                cO[((size_t)b * SEQ + qrow) * (NH * 64) + h * 64 + nt * 16 + l15] = O[mt][nt][r];
            }

    // q_coattn = P2^T @ Qp ; store
    s16x8 p2a[4][2];
#pragma unroll
    for (int mt = 0; mt < 4; ++mt)
#pragma unroll
        for (int ks = 0; ks < 2; ++ks)
            p2a[mt][ks] = *(const s16x8*)&Tw[TS(mt * 16 + l15, ks * 32 + l4 * 8)];

#pragma unroll
    for (int x = 0; x < 4; ++x)
#pragma unroll
        for (int y = 0; y < 4; ++y) O[x][y] = fz;
#pragma unroll
    for (int ks = 0; ks < 2; ++ks)
#pragma unroll
        for (int mt = 0; mt < 4; ++mt)
#pragma unroll
            for (int nt = 0; nt < 4; ++nt)
                O[mt][nt] = mma(p2a[mt][ks], qb[nt][ks], O[mt][nt]);

    float* qO = out + (size_t)NB * SEQ * NH * 64;
#pragma unroll
    for (int mt = 0; mt < 4; ++mt)
#pragma unroll
        for (int nt = 0; nt < 4; ++nt)
#pragma unroll
            for (int r = 0; r < 4; ++r) {
                int krow = mt * 16 + l4 * 4 + r;
                qO[((size_t)b * SEQ + krow) * (NH * 64) + h * 64 + nt * 16 + l15] = O[mt][nt][r];
            }

#undef STAGE
#undef GEMM16
}

extern "C" void kernel_launch(void* const* d_in, const int* in_sizes, int n_in,
                              void* d_out, int out_size, void* d_ws, size_t ws_size,
                              hipStream_t stream) {
    const float* query   = (const float*)d_in[0];
    const float* context = (const float*)d_in[1];
    const float* Wq      = (const float*)d_in[2];
    const float* bq      = (const float*)d_in[3];
    const float* Wc      = (const float*)d_in[4];
    const float* bc      = (const float*)d_in[5];
    float* out = (float*)d_out;

    unsigned short* wfrag = (unsigned short*)d_ws;   // 1 MB bf16 weight frags

    prep_weights<<<256, 256, 0, stream>>>(Wq, Wc, wfrag);
    fused_h<<<NB * 2, 256, 0, stream>>>(query, context, bq, bc, wfrag, out);
}

// Round 23
// 180.306 us; speedup vs baseline: 2.0821x; 2.0821x over previous
//
#include <hip/hip_runtime.h>
#include <hip/hip_bf16.h>

typedef float  f32x4 __attribute__((ext_vector_type(4)));
typedef short  s16x8 __attribute__((ext_vector_type(8)));

#define NB   1024
#define SEQ  64
#define DIM  512
#define NH   8
#define SCALE 0.044194173824159216f

// round-half-up f32->bf16: 2 VALU ops
static __device__ __forceinline__ unsigned short f2bf(float f) {
    unsigned u = __builtin_bit_cast(unsigned, f);
    return (unsigned short)((u + 0x8000u) >> 16);
}

static __device__ __forceinline__ f32x4 mma(s16x8 a, s16x8 b, f32x4 c) {
    return __builtin_amdgcn_mfma_f32_16x16x32_bf16(a, b, c, 0, 0, 0);
}

static __device__ __forceinline__ s16x8 cvt2(float4 a, float4 b) {
    s16x8 x;
    x[0] = (short)f2bf(a.x); x[1] = (short)f2bf(a.y);
    x[2] = (short)f2bf(a.z); x[3] = (short)f2bf(a.w);
    x[4] = (short)f2bf(b.x); x[5] = (short)f2bf(b.y);
    x[6] = (short)f2bf(b.z); x[7] = (short)f2bf(b.w);
    return x;
}

// Pre-kernel: Wq, Wc (f32 [512][512] row-major [k][n]) -> bf16 B-fragment order.
__global__ __launch_bounds__(256) void prep_weights(
    const float* __restrict__ Wq, const float* __restrict__ Wc,
    unsigned short* __restrict__ wf)
{
    int gid  = blockIdx.x * 256 + threadIdx.x;   // 0..65535
    int m    = gid >> 15;
    int tile = (gid >> 10) & 31;
    int ks   = (gid >> 6) & 15;
    int lane = gid & 63;
    const float* W = m ? Wc : Wq;
    int col = tile * 16 + (lane & 15);
    int k0  = ks * 32 + (lane >> 4) * 8;
    unsigned short* dst = wf + (size_t)gid * 8;
#pragma unroll
    for (int j = 0; j < 8; ++j)
        dst[j] = f2bf(W[(size_t)(k0 + j) * DIM + col]);
}

// ====================== Fused kernel: one block = one batch b ======================
// R13 VERBATIM — the empirical optimum of this design space (181.6-181.7 us,
// reproduced R13/R19). 512 threads, 8 waves = 8 heads. Phases:
//   1. stage query[b] AND context[b] tiles (64x512 f32) -> bf16 LDS, all 32
//      loads/thread hoisted, R12's verified zero-conflict XOR swizzle.
//   2. GEMM-C (16 K-steps, 64-AGPR acc) -> barrier -> Cp+bias -> per-wave
//      tail tile T (carved from the dead C region), cb frags to regs.
//   3. GEMM-Q reusing the SAME acc from Q-region; Qp+bias -> T; qa/qb frags.
//   4. in-register tail: Sc, both softmaxes, two outputs -> global.
// Total HBM = 256MB acts read + 268MB out write + weights (no intermediates).
//
// FAILED-mechanism ledger (all falsified with counters; do not revisit):
//  - min-waves __launch_bounds__ 2nd arg: clamps unified VGPR/AGPR below the
//    64-AGPR acc -> scratch spills (R2, R7: WRITE +100MB).
//  - multi-block co-residency: this kernel family sits at ~192-252 unified
//    regs/wave -> 8 waves/CU, ONE barrier group, regardless of LDS size
//    (R6/8/9/11/14; R21: 64KB LDS, occupancy unchanged; R22: 4-wave blocks
//    inflate per-wave staging regs to 188 -> HALF the waves, 375us).
//  - reg-held prefetch across the tail: >=32 VGPR held -> spill
//    (R15: WRITE 676MB; R18: WRITE 425MB).
//  - global_load_lds across barriers: vmcnt(0) drain before s_barrier kills
//    the overlap + traffic blowup (R16: FETCH 646MB).
//  - load staggering within one basic block: neutral (R17) — compiler
//    already batches the staging loads.
//  - sched_barrier(0) cross-lane fences: pin scheduling, extend live ranges
//    -> 186MB spill (R21). (R13's [64][72] layout needs no fence: verified
//    correct across R13/R19 runs.)
// Residual gap to the ~85us HBM floor (2.1x) = the serial per-block
// {read-stall -> compute -> store-drain} cycle; no plain-HIP mechanism at
// this register footprint can overlap it (all six falsified above).
__global__ __launch_bounds__(512) void fused_b(
    const float* __restrict__ query,
    const float* __restrict__ context,
    const float* __restrict__ bq,
    const float* __restrict__ bc,
    const unsigned short* __restrict__ wf,
    float* __restrict__ out)
{
    // 139264 B total: Q-stage 32768 shorts (64KB) + region2 36864 shorts
    // (72KB: C-stage uses first 64KB; 8 per-wave 64x72 tail tiles use all)
    __shared__ unsigned short smem[69632];
    unsigned short* Q = smem;
    unsigned short* C = smem + 32768;

    const int tid  = threadIdx.x;
    const int lane = tid & 63;
    const int wv   = tid >> 6;          // wave id = head
    const int l15  = lane & 15;
    const int l4   = lane >> 4;
    const int b    = blockIdx.x;

    const float* gq = query   + (size_t)b * SEQ * DIM;
    const float* gc = context + (size_t)b * SEQ * DIM;

    // ---------------- Phase 1: stage both tiles ----------------
    {
        const int row = tid >> 3;
        const int cw  = tid & 7;
        const int wsb = (cw >> 2) * 256 + (cw & 3) * 64 + row;
        const float* sq = gq + (size_t)row * DIM + cw * 8;
        const float* sc = gc + (size_t)row * DIM + cw * 8;
        float4 lq[16], lc[16];
#pragma unroll
        for (int p = 0; p < 8; ++p) {
            lq[2 * p]     = *(const float4*)(sq + p * 64);
            lq[2 * p + 1] = *(const float4*)(sq + p * 64 + 4);
        }
#pragma unroll
        for (int p = 0; p < 8; ++p) {
            lc[2 * p]     = *(const float4*)(sc + p * 64);
            lc[2 * p + 1] = *(const float4*)(sc + p * 64 + 4);
        }
#pragma unroll
        for (int p = 0; p < 8; ++p) {
            *(s16x8*)&Q[((p * 512 + wsb) ^ cw) * 8] = cvt2(lq[2 * p], lq[2 * p + 1]);
            *(s16x8*)&C[((p * 512 + wsb) ^ cw) * 8] = cvt2(lc[2 * p], lc[2 * p + 1]);
        }
    }
    __syncthreads();

    const f32x4 fz = {0.f, 0.f, 0.f, 0.f};
    f32x4 acc[4][4];

    // ---------------- Phase 2: GEMM-C ----------------
#pragma unroll
    for (int x = 0; x < 4; ++x)
#pragma unroll
        for (int y = 0; y < 4; ++y) acc[x][y] = fz;

    {
        const unsigned short* wfm = wf + 262144;   // Wc frags
#pragma unroll
        for (int ks = 0; ks < 16; ++ks) {
            const int p  = ks >> 1;
            const int kk = ks & 1;
            s16x8 af[4], bf[4];
#pragma unroll
            for (int mt = 0; mt < 4; ++mt) {
                const int s = p * 512 + kk * 256 + l4 * 64 + mt * 16 + l15;
                af[mt] = *(const s16x8*)&C[(s ^ (4 * kk + l4)) * 8];
            }
#pragma unroll
            for (int nt = 0; nt < 4; ++nt)
                bf[nt] = *(const s16x8*)(wfm +
                         ((size_t)((wv * 4 + nt) * 16 + ks) * 64 + lane) * 8);
#pragma unroll
            for (int mt = 0; mt < 4; ++mt)
#pragma unroll
                for (int nt = 0; nt < 4; ++nt)
                    acc[mt][nt] = mma(af[mt], bf[nt], acc[mt][nt]);
        }
    }
    __syncthreads();   // everyone done reading C-region before tail tiles land

    // per-wave 64x72 tail tile, carved from region2
    unsigned short (*T)[72] = (unsigned short(*)[72])(C + wv * 4608);

    // Cp + bias -> T ; cb frags (Cp^T as B operand: contiguous rows)
#pragma unroll
    for (int nt = 0; nt < 4; ++nt) {
        float bcv = bc[wv * 64 + nt * 16 + l15];
#pragma unroll
        for (int mt = 0; mt < 4; ++mt)
#pragma unroll
            for (int r = 0; r < 4; ++r)
                T[mt * 16 + l4 * 4 + r][nt * 16 + l15] = f2bf(acc[mt][nt][r] + bcv);
    }
    s16x8 cb[4][2];
#pragma unroll
    for (int nt = 0; nt < 4; ++nt)
#pragma unroll
        for (int ks = 0; ks < 2; ++ks)
            cb[nt][ks] = *(const s16x8*)&T[nt * 16 + l15][ks * 32 + l4 * 8];

    // ---------------- Phase 3: GEMM-Q (same acc regs) ----------------
#pragma unroll
    for (int x = 0; x < 4; ++x)
#pragma unroll
        for (int y = 0; y < 4; ++y) acc[x][y] = fz;

    {
#pragma unroll
        for (int ks = 0; ks < 16; ++ks) {
            const int p  = ks >> 1;
            const int kk = ks & 1;
            s16x8 af[4], bf[4];
#pragma unroll
            for (int mt = 0; mt < 4; ++mt) {
                const int s = p * 512 + kk * 256 + l4 * 64 + mt * 16 + l15;
                af[mt] = *(const s16x8*)&Q[(s ^ (4 * kk + l4)) * 8];
            }
#pragma unroll
            for (int nt = 0; nt < 4; ++nt)
                bf[nt] = *(const s16x8*)(wf +
                         ((size_t)((wv * 4 + nt) * 16 + ks) * 64 + lane) * 8);
#pragma unroll
            for (int mt = 0; mt < 4; ++mt)
#pragma unroll
                for (int nt = 0; nt < 4; ++nt)
                    acc[mt][nt] = mma(af[mt], bf[nt], acc[mt][nt]);
        }
    }

    // Qp + bias -> T (overwrites Cp; cb already in regs) ; qa/qb frags
#pragma unroll
    for (int nt = 0; nt < 4; ++nt) {
        float bqv = bq[wv * 64 + nt * 16 + l15];
#pragma unroll
        for (int mt = 0; mt < 4; ++mt)
#pragma unroll
            for (int r = 0; r < 4; ++r)
                T[mt * 16 + l4 * 4 + r][nt * 16 + l15] = f2bf(acc[mt][nt][r] + bqv);
    }
    s16x8 qa[4][2], qb[4][2];
#pragma unroll
    for (int mt = 0; mt < 4; ++mt)
#pragma unroll
        for (int ks = 0; ks < 2; ++ks)
            qa[mt][ks] = *(const s16x8*)&T[mt * 16 + l15][ks * 32 + l4 * 8];
#pragma unroll
    for (int nt = 0; nt < 4; ++nt)
#pragma unroll
        for (int ks = 0; ks < 2; ++ks) {
            s16x8 v;
#pragma unroll
            for (int j = 0; j < 8; ++j)
                v[j] = (short)T[ks * 32 + l4 * 8 + j][nt * 16 + l15];
            qb[nt][ks] = v;
        }

    // ---------------- Phase 4: attention tail ----------------
    f32x4 Sc[4][4];
#pragma unroll
    for (int x = 0; x < 4; ++x)
#pragma unroll
        for (int y = 0; y < 4; ++y) Sc[x][y] = fz;
#pragma unroll
    for (int ks = 0; ks < 2; ++ks)
#pragma unroll
        for (int mt = 0; mt < 4; ++mt)
#pragma unroll
            for (int nt = 0; nt < 4; ++nt)
                Sc[mt][nt] = mma(qa[mt][ks], cb[nt][ks], Sc[mt][nt]);

    // softmax over keys (rows): P1 -> T
#pragma unroll
    for (int mt = 0; mt < 4; ++mt)
#pragma unroll
        for (int r = 0; r < 4; ++r) {
            float m = fmaxf(fmaxf(Sc[mt][0][r], Sc[mt][1][r]),
                            fmaxf(Sc[mt][2][r], Sc[mt][3][r]));
            m = fmaxf(m, __shfl_xor(m, 1));
            m = fmaxf(m, __shfl_xor(m, 2));
            m = fmaxf(m, __shfl_xor(m, 4));
            m = fmaxf(m, __shfl_xor(m, 8));
            float e[4], s = 0.f;
#pragma unroll
            for (int nt = 0; nt < 4; ++nt) { e[nt] = __expf(SCALE * (Sc[mt][nt][r] - m)); s += e[nt]; }
            s += __shfl_xor(s, 1);
            s += __shfl_xor(s, 2);
            s += __shfl_xor(s, 4);
            s += __shfl_xor(s, 8);
            float inv = 1.f / s;
            int row = mt * 16 + l4 * 4 + r;
#pragma unroll
            for (int nt = 0; nt < 4; ++nt)
                T[row][nt * 16 + l15] = f2bf(e[nt] * inv);
        }

    s16x8 pa[4][2];
#pragma unroll
    for (int mt = 0; mt < 4; ++mt)
#pragma unroll
        for (int ks = 0; ks < 2; ++ks)
            pa[mt][ks] = *(const s16x8*)&T[mt * 16 + l15][ks * 32 + l4 * 8];

    // softmax over queries (cols): P2^T -> T
#pragma unroll
    for (int nt = 0; nt < 4; ++nt) {
        float m = -1e30f;
#pragma unroll
        for (int mt = 0; mt < 4; ++mt)
#pragma unroll
            for (int r = 0; r < 4; ++r) m = fmaxf(m, Sc[mt][nt][r]);
        m = fmaxf(m, __shfl_xor(m, 16));
        m = fmaxf(m, __shfl_xor(m, 32));
        float ee[4][4], s = 0.f;
#pragma unroll
        for (int mt = 0; mt < 4; ++mt)
#pragma unroll
            for (int r = 0; r < 4; ++r) { ee[mt][r] = __expf(SCALE * (Sc[mt][nt][r] - m)); s += ee[mt][r]; }
        s += __shfl_xor(s, 16);
        s += __shfl_xor(s, 32);
        float inv = 1.f / s;
        int krow = nt * 16 + l15;
#pragma unroll
        for (int mt = 0; mt < 4; ++mt)
#pragma unroll
            for (int r = 0; r < 4; ++r)
                T[krow][mt * 16 + l4 * 4 + r] = f2bf(ee[mt][r] * inv);
    }

    // c_coattn = P1 @ Cp^T ; store
    f32x4 O[4][4];
#pragma unroll
    for (int x = 0; x < 4; ++x)
#pragma unroll
        for (int y = 0; y < 4; ++y) O[x][y] = fz;
#pragma unroll
    for (int ks = 0; ks < 2; ++ks)
#pragma unroll
        for (int mt = 0; mt < 4; ++mt)
#pragma unroll
            for (int nt = 0; nt < 4; ++nt)
                O[mt][nt] = mma(pa[mt][ks], cb[nt][ks], O[mt][nt]);

    float* cO = out;
#pragma unroll
    for (int mt = 0; mt < 4; ++mt)
#pragma unroll
        for (int nt = 0; nt < 4; ++nt)
#pragma unroll
            for (int r = 0; r < 4; ++r) {
                int qrow = mt * 16 + l4 * 4 + r;
                cO[((size_t)b * SEQ + qrow) * (NH * 64) + wv * 64 + nt * 16 + l15] = O[mt][nt][r];
            }

    // q_coattn = P2^T @ Qp ; store
    s16x8 p2a[4][2];
#pragma unroll
    for (int mt = 0; mt < 4; ++mt)
#pragma unroll
        for (int ks = 0; ks < 2; ++ks)
            p2a[mt][ks] = *(const s16x8*)&T[mt * 16 + l15][ks * 32 + l4 * 8];

#pragma unroll
    for (int x = 0; x < 4; ++x)
#pragma unroll
        for (int y = 0; y < 4; ++y) O[x][y] = fz;
#pragma unroll
    for (int ks = 0; ks < 2; ++ks)
#pragma unroll
        for (int mt = 0; mt < 4; ++mt)
#pragma unroll
            for (int nt = 0; nt < 4; ++nt)
                O[mt][nt] = mma(p2a[mt][ks], qb[nt][ks], O[mt][nt]);

    float* qO = out + (size_t)NB * SEQ * NH * 64;
#pragma unroll
    for (int mt = 0; mt < 4; ++mt)
#pragma unroll
        for (int nt = 0; nt < 4; ++nt)
#pragma unroll
            for (int r = 0; r < 4; ++r) {
                int krow = mt * 16 + l4 * 4 + r;
                qO[((size_t)b * SEQ + krow) * (NH * 64) + wv * 64 + nt * 16 + l15] = O[mt][nt][r];
            }
}

extern "C" void kernel_launch(void* const* d_in, const int* in_sizes, int n_in,
                              void* d_out, int out_size, void* d_ws, size_t ws_size,
                              hipStream_t stream) {
    const float* query   = (const float*)d_in[0];
    const float* context = (const float*)d_in[1];
    const float* Wq      = (const float*)d_in[2];
    const float* bq      = (const float*)d_in[3];
    const float* Wc      = (const float*)d_in[4];
    const float* bc      = (const float*)d_in[5];
    float* out = (float*)d_out;

    unsigned short* wfrag = (unsigned short*)d_ws;   // 1 MB bf16 weight frags

    prep_weights<<<256, 256, 0, stream>>>(Wq, Wc, wfrag);
    fused_b<<<NB, 512, 0, stream>>>(query, context, bq, bc, wfrag, out);
}